// Round 1
// baseline (918.675 us; speedup 1.0000x reference)
//
#include <hip/hip_runtime.h>
#include <hip/hip_bf16.h>
#include <cmath>

#define BB 4
#define SS 2048
#define DD 1024
#define BS (BB*SS)            // 8192 rows total
constexpr float EPS = 1e-6f;

// ---------------------------------------------------------------------------
// K1: LayerNorm (unbiased var, gamma*(x-mean)/(sqrt(var)+eps)+beta) -> bf16 x
// one block (256 threads) per row of D=1024
// ---------------------------------------------------------------------------
__global__ __launch_bounds__(256)
void ln_kernel(const float* __restrict__ ctx, const float* __restrict__ gamma,
               const float* __restrict__ beta, __hip_bfloat16* __restrict__ xo) {
    int row = blockIdx.x;
    int t = threadIdx.x;
    const float* r = ctx + (size_t)row * DD;
    float4 v = ((const float4*)r)[t];
    float s1 = v.x + v.y + v.z + v.w;
    float s2 = v.x*v.x + v.y*v.y + v.z*v.z + v.w*v.w;
    #pragma unroll
    for (int off = 32; off; off >>= 1) {
        s1 += __shfl_down(s1, off);
        s2 += __shfl_down(s2, off);
    }
    __shared__ float ls1[4], ls2[4];
    int wid = t >> 6, lane = t & 63;
    if (lane == 0) { ls1[wid] = s1; ls2[wid] = s2; }
    __syncthreads();
    if (t == 0) {
        float a = ls1[0] + ls1[1] + ls1[2] + ls1[3];
        float b = ls2[0] + ls2[1] + ls2[2] + ls2[3];
        float mean = a / DD;
        float var = (b - a * a / DD) / (DD - 1);
        ls1[0] = mean;
        ls2[0] = 1.0f / (sqrtf(var) + EPS);
    }
    __syncthreads();
    float mean = ls1[0], rstd = ls2[0];
    float4 g = ((const float4*)gamma)[t];
    float4 be = ((const float4*)beta)[t];
    union { ushort4 u; __hip_bfloat16 h[4]; } pk;
    pk.h[0] = __float2bfloat16(g.x * (v.x - mean) * rstd + be.x);
    pk.h[1] = __float2bfloat16(g.y * (v.y - mean) * rstd + be.y);
    pk.h[2] = __float2bfloat16(g.z * (v.z - mean) * rstd + be.z);
    pk.h[3] = __float2bfloat16(g.w * (v.w - mean) * rstd + be.w);
    ((ushort4*)(xo + (size_t)row * DD))[t] = pk.u;
}

// ---------------------------------------------------------------------------
// K2: C[8192 x 2048] = x @ [Wq | Wk] + [bq | bk]  (fp32 compute, bf16 in/out)
// 64x64 tiles, BK=16, 256 threads, 4x4 microtile
// ---------------------------------------------------------------------------
#define BM 64
#define BN 64
#define BK 16
__global__ __launch_bounds__(256)
void gemm_kernel(const __hip_bfloat16* __restrict__ X, const float* __restrict__ Wq,
                 const float* __restrict__ Wk, const float* __restrict__ bq,
                 const float* __restrict__ bk, __hip_bfloat16* __restrict__ Cout) {
    __shared__ float As[BK][BM + 1];
    __shared__ float Bsh[BK][BN + 1];
    int bm = blockIdx.x;          // 0..127
    int bn = blockIdx.y;          // 0..31
    int tid = threadIdx.x;
    int tx = tid & 15, ty = tid >> 4;
    int n0 = bn * BN;             // absolute col in [0,2048)
    const float* W = (n0 < DD) ? Wq : Wk;
    const float* bias = (n0 < DD) ? bq : bk;
    int ncol0 = (n0 < DD) ? n0 : n0 - DD;
    float acc[4][4] = {};
    for (int k0 = 0; k0 < DD; k0 += BK) {
        {   // A tile: 64 rows x 16 k (bf16 -> f32)
            int lrow = tid >> 2, lk = (tid & 3) * 4;
            const __hip_bfloat16* src = X + (size_t)(bm * BM + lrow) * DD + k0 + lk;
            union { ushort4 u; __hip_bfloat16 h[4]; } cv;
            cv.u = *(const ushort4*)src;
            As[lk + 0][lrow] = __bfloat162float(cv.h[0]);
            As[lk + 1][lrow] = __bfloat162float(cv.h[1]);
            As[lk + 2][lrow] = __bfloat162float(cv.h[2]);
            As[lk + 3][lrow] = __bfloat162float(cv.h[3]);
        }
        {   // B tile: 16 k x 64 cols (f32)
            int lk = tid >> 4, lcol = (tid & 15) * 4;
            const float* src = W + (size_t)(k0 + lk) * DD + ncol0 + lcol;
            float4 v = *(const float4*)src;
            Bsh[lk][lcol + 0] = v.x;
            Bsh[lk][lcol + 1] = v.y;
            Bsh[lk][lcol + 2] = v.z;
            Bsh[lk][lcol + 3] = v.w;
        }
        __syncthreads();
        #pragma unroll
        for (int kk = 0; kk < BK; ++kk) {
            float a[4], b[4];
            #pragma unroll
            for (int r = 0; r < 4; ++r) a[r] = As[kk][ty * 4 + r];
            #pragma unroll
            for (int c = 0; c < 4; ++c) b[c] = Bsh[kk][tx * 4 + c];
            #pragma unroll
            for (int r = 0; r < 4; ++r)
                #pragma unroll
                for (int c = 0; c < 4; ++c)
                    acc[r][c] += a[r] * b[c];
        }
        __syncthreads();
    }
    #pragma unroll
    for (int r = 0; r < 4; ++r) {
        int row = bm * BM + ty * 4 + r;
        union { ushort4 u; __hip_bfloat16 h[4]; } pk;
        #pragma unroll
        for (int c = 0; c < 4; ++c)
            pk.h[c] = __float2bfloat16(acc[r][c] + bias[ncol0 + tx * 4 + c]);
        *(ushort4*)(Cout + (size_t)row * (2 * DD) + n0 + tx * 4) = pk.u;
    }
}

// ---------------------------------------------------------------------------
// K3: band scores + 2-entry softmax -> v_sub, v_sup, w  (one wave per row)
// C layout: row gw has q at cols [0,1024), k at [1024,2048)
// ---------------------------------------------------------------------------
__global__ __launch_bounds__(256)
void band_kernel(const __hip_bfloat16* __restrict__ C, const int* __restrict__ eos,
                 float* __restrict__ vsub, float* __restrict__ vsup,
                 float* __restrict__ wuni) {
    int gw = (blockIdx.x * blockDim.x + threadIdx.x) >> 6;  // row id 0..BS-1
    int lane = threadIdx.x & 63;
    int i = gw & (SS - 1);
    float qv[16];
    {
        const ushort4* p = (const ushort4*)(C + (size_t)gw * (2 * DD) + lane * 16);
        #pragma unroll
        for (int m = 0; m < 4; ++m) {
            union { ushort4 u; __hip_bfloat16 h[4]; } cv; cv.u = p[m];
            #pragma unroll
            for (int r = 0; r < 4; ++r) qv[m * 4 + r] = __bfloat162float(cv.h[r]);
        }
    }
    float ssup = 0.f, ssub = 0.f;
    if (i < SS - 1) {
        const ushort4* p = (const ushort4*)(C + (size_t)(gw + 1) * (2 * DD) + DD + lane * 16);
        #pragma unroll
        for (int m = 0; m < 4; ++m) {
            union { ushort4 u; __hip_bfloat16 h[4]; } cv; cv.u = p[m];
            #pragma unroll
            for (int r = 0; r < 4; ++r) ssup += qv[m * 4 + r] * __bfloat162float(cv.h[r]);
        }
    }
    if (i > 0) {
        const ushort4* p = (const ushort4*)(C + (size_t)(gw - 1) * (2 * DD) + DD + lane * 16);
        #pragma unroll
        for (int m = 0; m < 4; ++m) {
            union { ushort4 u; __hip_bfloat16 h[4]; } cv; cv.u = p[m];
            #pragma unroll
            for (int r = 0; r < 4; ++r) ssub += qv[m * 4 + r] * __bfloat162float(cv.h[r]);
        }
    }
    #pragma unroll
    for (int off = 32; off; off >>= 1) {
        ssup += __shfl_down(ssup, off);
        ssub += __shfl_down(ssub, off);
    }
    if (lane == 0) {
        ssup *= (1.0f / DD);
        ssub *= (1.0f / DD);
        bool msub = (i > 0) && (eos[(size_t)gw * SS + (i - 1)] != 0);
        bool msup = (i < SS - 1) && (eos[(size_t)gw * SS + (i + 1)] != 0);
        float vs, vp, w;
        if (msub && msup) {
            float mx = fmaxf(ssub, ssup);
            float e1 = expf(ssub - mx), e2 = expf(ssup - mx);
            float inv = 1.0f / (e1 + e2);
            vs = e1 * inv; vp = e2 * inv; w = 0.f;
        } else if (msub) { vs = 1.f; vp = 0.f; w = 0.f; }
        else if (msup)   { vs = 0.f; vp = 1.f; w = 0.f; }
        else             { vs = vp = w = 1.0f / SS; }
        vsub[gw] = vs; vsup[gw] = vp; wuni[gw] = w;
    }
}

// ---------------------------------------------------------------------------
// K4: per batch, Lc[i] = sum_{t<i} log(na3[t,t+1] + 1e-9)  (double precision)
// one block (256 threads) per batch; Hillis-Steele scan over 256 partials
// ---------------------------------------------------------------------------
__global__ __launch_bounds__(256)
void scan_kernel(const float* __restrict__ prior, const float* __restrict__ vsub,
                 const float* __restrict__ vsup, double* __restrict__ Lc) {
    int b = blockIdx.x;
    int t = threadIdx.x;
    double loc[8];
    double s = 0.0;
    #pragma unroll
    for (int k = 0; k < 8; ++k) {
        int tt = t * 8 + k;
        double Lv = 0.0;
        if (tt < SS - 1) {
            float pr = prior[((size_t)(b * SS + tt)) * SS + tt + 1];
            float na2 = sqrtf(vsup[b * SS + tt] * vsub[b * SS + tt + 1] + 1e-9f);
            float P = pr + (1.f - pr) * na2;
            Lv = log((double)P + 1e-9);
        }
        loc[k] = Lv; s += Lv;
    }
    __shared__ double sa[256], sb[256];
    sa[t] = s;
    __syncthreads();
    double* src = sa; double* dst = sb;
    for (int off = 1; off < 256; off <<= 1) {
        double v = src[t];
        if (t >= off) v += src[t - off];
        __syncthreads();
        dst[t] = v;
        __syncthreads();
        double* tmp = src; src = dst; dst = tmp;
    }
    double run = (t == 0) ? 0.0 : src[t - 1];
    #pragma unroll
    for (int k = 0; k < 8; ++k) {
        int idx = t * 8 + k;
        Lc[b * SS + idx] = run;   // exclusive prefix
        run += loc[k];
    }
}

// ---------------------------------------------------------------------------
// K5: fused output pass: na3 (dense) and g_attn, 4 cols per thread
// ---------------------------------------------------------------------------
__global__ __launch_bounds__(256)
void out_kernel(const float* __restrict__ prior, const float* __restrict__ vsub,
                const float* __restrict__ vsup, const float* __restrict__ wuni,
                const double* __restrict__ Lc, float* __restrict__ out_g,
                float* __restrict__ out_na) {
    size_t gid = (size_t)blockIdx.x * 256 + threadIdx.x;   // 0 .. B*S*S/4-1
    int jt = (int)(gid & 511);
    int row = (int)(gid >> 9);          // b*S + i
    int i = row & (SS - 1);
    int b = row >> 11;
    int j0 = jt * 4;
    size_t base = (size_t)row * SS + j0;
    float4 pr4 = *(const float4*)(prior + base);
    float4 wj4 = *(const float4*)(wuni + b * SS + j0);
    float pra[4] = {pr4.x, pr4.y, pr4.z, pr4.w};
    float wja[4] = {wj4.x, wj4.y, wj4.z, wj4.w};
    float wi = wuni[row];
    double Lci = Lc[row];
    const double* Lcb = Lc + b * SS;
    float nav[4], gv[4];
    #pragma unroll
    for (int c = 0; c < 4; ++c) {
        int j = j0 + c;
        float prod;
        if (j == i - 1)      prod = vsub[row] * vsup[row - 1];
        else if (j == i + 1) prod = vsup[row] * vsub[row + 1];
        else if (j == i)     prod = wi * wi;
        else                 prod = wi * wja[c];
        float na2 = sqrtf(prod + 1e-9f);
        float p = pra[c];
        float na3 = p + (1.f - p) * na2;
        nav[c] = na3;
        if (j == i) {
            gv[c] = na3;
        } else {
            double d = (j > i) ? (Lcb[j] - Lci) : (Lci - Lcb[j]);
            gv[c] = expf((float)d) + 1e-9f;
        }
    }
    *(float4*)(out_g + base) = make_float4(gv[0], gv[1], gv[2], gv[3]);
    *(float4*)(out_na + base) = make_float4(nav[0], nav[1], nav[2], nav[3]);
}

// ---------------------------------------------------------------------------
extern "C" void kernel_launch(void* const* d_in, const int* in_sizes, int n_in,
                              void* d_out, int out_size, void* d_ws, size_t ws_size,
                              hipStream_t stream) {
    const float* ctx   = (const float*)d_in[0];
    const int*   eos   = (const int*)d_in[1];
    const float* prior = (const float*)d_in[2];
    const float* Wq    = (const float*)d_in[3];
    const float* bq    = (const float*)d_in[4];
    const float* Wk    = (const float*)d_in[5];
    const float* bk    = (const float*)d_in[6];
    const float* gamma = (const float*)d_in[7];
    const float* beta  = (const float*)d_in[8];

    float* out_g  = (float*)d_out;
    float* out_na = out_g + (size_t)BB * SS * SS;

    char* ws = (char*)d_ws;
    __hip_bfloat16* x = (__hip_bfloat16*)ws;                               // 16 MiB
    __hip_bfloat16* C = (__hip_bfloat16*)(ws + (size_t)BS * DD * 2);       // 32 MiB
    char* p2 = ws + (size_t)BS * DD * 2 + (size_t)BS * 2 * DD * 2;
    float* vsub = (float*)p2;
    float* vsup = vsub + BS;
    float* wuni = vsup + BS;
    double* Lc = (double*)(p2 + 3 * (size_t)BS * 4);

    ln_kernel<<<BS, 256, 0, stream>>>(ctx, gamma, beta, x);

    dim3 g2(BS / BM, (2 * DD) / BN);
    gemm_kernel<<<g2, 256, 0, stream>>>(x, Wq, Wk, bq, bk, C);

    band_kernel<<<BS / 4, 256, 0, stream>>>(C, eos, vsub, vsup, wuni);

    scan_kernel<<<BB, 256, 0, stream>>>(prior, vsub, vsup, Lc);

    size_t total = (size_t)BB * SS * SS / 4;
    out_kernel<<<(int)(total / 256), 256, 0, stream>>>(prior, vsub, vsup, wuni, Lc,
                                                       out_g, out_na);
}

// Round 2
// 336.664 us; speedup vs baseline: 2.7288x; 2.7288x over previous
//
#include <hip/hip_runtime.h>
#include <hip/hip_bf16.h>
#include <cmath>

#define BB 4
#define SS 2048
#define DD 1024
#define NN 2048               // Wq|Wk combined output cols
#define BS (BB*SS)            // 8192 rows total
constexpr float EPS = 1e-6f;

typedef __attribute__((ext_vector_type(8))) short short8;
typedef __attribute__((ext_vector_type(4))) float floatx4;

// ---------------------------------------------------------------------------
// K1: LayerNorm (unbiased var) -> bf16 x ; one block (256 thr) per row D=1024
// ---------------------------------------------------------------------------
__global__ __launch_bounds__(256)
void ln_kernel(const float* __restrict__ ctx, const float* __restrict__ gamma,
               const float* __restrict__ beta, __hip_bfloat16* __restrict__ xo) {
    int row = blockIdx.x;
    int t = threadIdx.x;
    const float* r = ctx + (size_t)row * DD;
    float4 v = ((const float4*)r)[t];
    float s1 = v.x + v.y + v.z + v.w;
    float s2 = v.x*v.x + v.y*v.y + v.z*v.z + v.w*v.w;
    #pragma unroll
    for (int off = 32; off; off >>= 1) {
        s1 += __shfl_down(s1, off);
        s2 += __shfl_down(s2, off);
    }
    __shared__ float ls1[4], ls2[4];
    int wid = t >> 6, lane = t & 63;
    if (lane == 0) { ls1[wid] = s1; ls2[wid] = s2; }
    __syncthreads();
    if (t == 0) {
        float a = ls1[0] + ls1[1] + ls1[2] + ls1[3];
        float b = ls2[0] + ls2[1] + ls2[2] + ls2[3];
        float mean = a / DD;
        float var = (b - a * a / DD) / (DD - 1);
        ls1[0] = mean;
        ls2[0] = 1.0f / (sqrtf(var) + EPS);
    }
    __syncthreads();
    float mean = ls1[0], rstd = ls2[0];
    float4 g = ((const float4*)gamma)[t];
    float4 be = ((const float4*)beta)[t];
    union { ushort4 u; __hip_bfloat16 h[4]; } pk;
    pk.h[0] = __float2bfloat16(g.x * (v.x - mean) * rstd + be.x);
    pk.h[1] = __float2bfloat16(g.y * (v.y - mean) * rstd + be.y);
    pk.h[2] = __float2bfloat16(g.z * (v.z - mean) * rstd + be.z);
    pk.h[3] = __float2bfloat16(g.w * (v.w - mean) * rstd + be.w);
    ((ushort4*)(xo + (size_t)row * DD))[t] = pk.u;
}

// ---------------------------------------------------------------------------
// K2a: transpose+convert W -> WT bf16 [N=2048][K=1024]; WT[n][k] = W[k][n]
// grid (K/32, N/32), 256 threads, LDS 32x33 tile
// ---------------------------------------------------------------------------
__global__ __launch_bounds__(256)
void prep_kernel(const float* __restrict__ Wq, const float* __restrict__ Wk,
                 __hip_bfloat16* __restrict__ WT) {
    __shared__ float tile[32][33];
    int kt = blockIdx.x * 32;
    int nt = blockIdx.y * 32;
    int t = threadIdx.x;
    int lr = t >> 3;          // 0..31
    int lc = (t & 7) * 4;     // 0,4,..,28
    const float* W = (nt < DD) ? Wq : Wk;
    int nsrc = (nt < DD) ? nt : nt - DD;
    float4 v = *(const float4*)(W + (size_t)(kt + lr) * DD + nsrc + lc);
    tile[lr][lc + 0] = v.x;
    tile[lr][lc + 1] = v.y;
    tile[lr][lc + 2] = v.z;
    tile[lr][lc + 3] = v.w;
    __syncthreads();
    // write row n = nt+lr, cols k = kt+lc..+3
    union { ushort4 u; __hip_bfloat16 h[4]; } pk;
    pk.h[0] = __float2bfloat16(tile[lc + 0][lr]);
    pk.h[1] = __float2bfloat16(tile[lc + 1][lr]);
    pk.h[2] = __float2bfloat16(tile[lc + 2][lr]);
    pk.h[3] = __float2bfloat16(tile[lc + 3][lr]);
    *(ushort4*)(WT + (size_t)(nt + lr) * DD + kt + lc) = pk.u;
}

// K2b: combined bias (fp32)
__global__ __launch_bounds__(256)
void bias_kernel(const float* __restrict__ bq, const float* __restrict__ bk,
                 float* __restrict__ biasc) {
    int i = blockIdx.x * 256 + threadIdx.x;
    biasc[i] = (i < DD) ? bq[i] : bk[i - DD];
}

// ---------------------------------------------------------------------------
// K3: MFMA GEMM  C[8192 x 2048] = X @ [Wq|Wk] + bias  (bf16 in/out, f32 acc)
// 128x128 block, 4 waves of 64x64, BK=32, mfma_f32_16x16x32_bf16
// ---------------------------------------------------------------------------
#define TM 128
#define TN 128
#define TK 32
__global__ __launch_bounds__(256, 1)
void gemm_mfma(const __hip_bfloat16* __restrict__ X,
               const __hip_bfloat16* __restrict__ WT,
               const float* __restrict__ biasc,
               __hip_bfloat16* __restrict__ C) {
    __shared__ short As[TM * TK];   // [row][k], row stride 32 shorts (64 B)
    __shared__ short Bs[TN * TK];   // [n][k]
    int tid = threadIdx.x;
    int wave = tid >> 6;
    int lane = tid & 63;
    int wm = wave >> 1, wn = wave & 1;
    int q = lane >> 4, m16 = lane & 15;

    // staging source: lane l covers row (l>>2), k-offset (l&3)*8 within a 16-row chunk
    int srow = lane >> 2;
    int skoff = (lane & 3) * 8;
    const __hip_bfloat16* gA = X + ((size_t)blockIdx.x * TM + wave * 32 + srow) * DD + skoff;
    const __hip_bfloat16* gB = WT + ((size_t)blockIdx.y * TN + wave * 32 + srow) * DD + skoff;
    short* lAbase = As + (wave * 32) * TK;   // wave-uniform
    short* lBbase = Bs + (wave * 32) * TK;

    floatx4 acc[4][4] = {};

    for (int k0 = 0; k0 < DD; k0 += TK) {
        __builtin_amdgcn_global_load_lds(
            (const __attribute__((address_space(1))) void*)(gA + k0),
            (__attribute__((address_space(3))) void*)(lAbase), 16, 0, 0);
        __builtin_amdgcn_global_load_lds(
            (const __attribute__((address_space(1))) void*)(gA + k0 + 16 * DD),
            (__attribute__((address_space(3))) void*)(lAbase + 16 * TK), 16, 0, 0);
        __builtin_amdgcn_global_load_lds(
            (const __attribute__((address_space(1))) void*)(gB + k0),
            (__attribute__((address_space(3))) void*)(lBbase), 16, 0, 0);
        __builtin_amdgcn_global_load_lds(
            (const __attribute__((address_space(1))) void*)(gB + k0 + 16 * DD),
            (__attribute__((address_space(3))) void*)(lBbase + 16 * TK), 16, 0, 0);
        __syncthreads();
        short8 af[4], bf[4];
        #pragma unroll
        for (int r = 0; r < 4; ++r)
            af[r] = *(const short8*)(As + (wm * 64 + r * 16 + m16) * TK + q * 8);
        #pragma unroll
        for (int c = 0; c < 4; ++c)
            bf[c] = *(const short8*)(Bs + (wn * 64 + c * 16 + m16) * TK + q * 8);
        #pragma unroll
        for (int r = 0; r < 4; ++r)
            #pragma unroll
            for (int c = 0; c < 4; ++c)
                acc[r][c] = __builtin_amdgcn_mfma_f32_16x16x32_bf16(af[r], bf[c], acc[r][c], 0, 0, 0);
        __syncthreads();
    }

    // epilogue: C/D layout col = lane&15, row = (lane>>4)*4 + reg
    int gcol0 = blockIdx.y * TN + wn * 64 + m16;
    int growb = blockIdx.x * TM + wm * 64 + q * 4;
    #pragma unroll
    for (int r = 0; r < 4; ++r) {
        #pragma unroll
        for (int c = 0; c < 4; ++c) {
            int gcol = gcol0 + c * 16;
            float bval = biasc[gcol];
            #pragma unroll
            for (int e = 0; e < 4; ++e) {
                int grow = growb + r * 16 + e;
                C[(size_t)grow * NN + gcol] = __float2bfloat16(acc[r][c][e] + bval);
            }
        }
    }
}

// ---------------------------------------------------------------------------
// K4: band scores + 2-entry softmax -> v_sub, v_sup, w  (one wave per row)
// ---------------------------------------------------------------------------
__global__ __launch_bounds__(256)
void band_kernel(const __hip_bfloat16* __restrict__ C, const int* __restrict__ eos,
                 float* __restrict__ vsub, float* __restrict__ vsup,
                 float* __restrict__ wuni) {
    int gw = (blockIdx.x * blockDim.x + threadIdx.x) >> 6;  // row id 0..BS-1
    int lane = threadIdx.x & 63;
    int i = gw & (SS - 1);
    float qv[16];
    {
        const ushort4* p = (const ushort4*)(C + (size_t)gw * NN + lane * 16);
        #pragma unroll
        for (int m = 0; m < 4; ++m) {
            union { ushort4 u; __hip_bfloat16 h[4]; } cv; cv.u = p[m];
            #pragma unroll
            for (int r = 0; r < 4; ++r) qv[m * 4 + r] = __bfloat162float(cv.h[r]);
        }
    }
    float ssup = 0.f, ssub = 0.f;
    if (i < SS - 1) {
        const ushort4* p = (const ushort4*)(C + (size_t)(gw + 1) * NN + DD + lane * 16);
        #pragma unroll
        for (int m = 0; m < 4; ++m) {
            union { ushort4 u; __hip_bfloat16 h[4]; } cv; cv.u = p[m];
            #pragma unroll
            for (int r = 0; r < 4; ++r) ssup += qv[m * 4 + r] * __bfloat162float(cv.h[r]);
        }
    }
    if (i > 0) {
        const ushort4* p = (const ushort4*)(C + (size_t)(gw - 1) * NN + DD + lane * 16);
        #pragma unroll
        for (int m = 0; m < 4; ++m) {
            union { ushort4 u; __hip_bfloat16 h[4]; } cv; cv.u = p[m];
            #pragma unroll
            for (int r = 0; r < 4; ++r) ssub += qv[m * 4 + r] * __bfloat162float(cv.h[r]);
        }
    }
    #pragma unroll
    for (int off = 32; off; off >>= 1) {
        ssup += __shfl_down(ssup, off);
        ssub += __shfl_down(ssub, off);
    }
    if (lane == 0) {
        ssup *= (1.0f / DD);
        ssub *= (1.0f / DD);
        bool msub = (i > 0) && (eos[(size_t)gw * SS + (i - 1)] != 0);
        bool msup = (i < SS - 1) && (eos[(size_t)gw * SS + (i + 1)] != 0);
        float vs, vp, w;
        if (msub && msup) {
            float mx = fmaxf(ssub, ssup);
            float e1 = expf(ssub - mx), e2 = expf(ssup - mx);
            float inv = 1.0f / (e1 + e2);
            vs = e1 * inv; vp = e2 * inv; w = 0.f;
        } else if (msub) { vs = 1.f; vp = 0.f; w = 0.f; }
        else if (msup)   { vs = 0.f; vp = 1.f; w = 0.f; }
        else             { vs = vp = w = 1.0f / SS; }
        vsub[gw] = vs; vsup[gw] = vp; wuni[gw] = w;
    }
}

// ---------------------------------------------------------------------------
// K5: per batch, Lc[i] = sum_{t<i} log(na3[t,t+1] + 1e-9)  (double precision)
// ---------------------------------------------------------------------------
__global__ __launch_bounds__(256)
void scan_kernel(const float* __restrict__ prior, const float* __restrict__ vsub,
                 const float* __restrict__ vsup, double* __restrict__ Lc) {
    int b = blockIdx.x;
    int t = threadIdx.x;
    double loc[8];
    double s = 0.0;
    #pragma unroll
    for (int k = 0; k < 8; ++k) {
        int tt = t * 8 + k;
        double Lv = 0.0;
        if (tt < SS - 1) {
            float pr = prior[((size_t)(b * SS + tt)) * SS + tt + 1];
            float na2 = sqrtf(vsup[b * SS + tt] * vsub[b * SS + tt + 1] + 1e-9f);
            float P = pr + (1.f - pr) * na2;
            Lv = log((double)P + 1e-9);
        }
        loc[k] = Lv; s += Lv;
    }
    __shared__ double sa[256], sb[256];
    sa[t] = s;
    __syncthreads();
    double* src = sa; double* dst = sb;
    for (int off = 1; off < 256; off <<= 1) {
        double v = src[t];
        if (t >= off) v += src[t - off];
        __syncthreads();
        dst[t] = v;
        __syncthreads();
        double* tmp = src; src = dst; dst = tmp;
    }
    double run = (t == 0) ? 0.0 : src[t - 1];
    #pragma unroll
    for (int k = 0; k < 8; ++k) {
        int idx = t * 8 + k;
        Lc[b * SS + idx] = run;   // exclusive prefix
        run += loc[k];
    }
}

// ---------------------------------------------------------------------------
// K6: fused output pass: na3 (dense) and g_attn, 4 cols per thread
// ---------------------------------------------------------------------------
__global__ __launch_bounds__(256)
void out_kernel(const float* __restrict__ prior, const float* __restrict__ vsub,
                const float* __restrict__ vsup, const float* __restrict__ wuni,
                const double* __restrict__ Lc, float* __restrict__ out_g,
                float* __restrict__ out_na) {
    size_t gid = (size_t)blockIdx.x * 256 + threadIdx.x;   // 0 .. B*S*S/4-1
    int jt = (int)(gid & 511);
    int row = (int)(gid >> 9);          // b*S + i
    int i = row & (SS - 1);
    int b = row >> 11;
    int j0 = jt * 4;
    size_t base = (size_t)row * SS + j0;
    float4 pr4 = *(const float4*)(prior + base);
    float4 wj4 = *(const float4*)(wuni + b * SS + j0);
    float pra[4] = {pr4.x, pr4.y, pr4.z, pr4.w};
    float wja[4] = {wj4.x, wj4.y, wj4.z, wj4.w};
    float wi = wuni[row];
    double Lci = Lc[row];
    const double* Lcb = Lc + b * SS;
    float nav[4], gv[4];
    #pragma unroll
    for (int c = 0; c < 4; ++c) {
        int j = j0 + c;
        float prod;
        if (j == i - 1)      prod = vsub[row] * vsup[row - 1];
        else if (j == i + 1) prod = vsup[row] * vsub[row + 1];
        else if (j == i)     prod = wi * wi;
        else                 prod = wi * wja[c];
        float na2 = sqrtf(prod + 1e-9f);
        float p = pra[c];
        float na3 = p + (1.f - p) * na2;
        nav[c] = na3;
        if (j == i) {
            gv[c] = na3;
        } else {
            double d = (j > i) ? (Lcb[j] - Lci) : (Lci - Lcb[j]);
            gv[c] = expf((float)d) + 1e-9f;
        }
    }
    *(float4*)(out_g + base) = make_float4(gv[0], gv[1], gv[2], gv[3]);
    *(float4*)(out_na + base) = make_float4(nav[0], nav[1], nav[2], nav[3]);
}

// ---------------------------------------------------------------------------
extern "C" void kernel_launch(void* const* d_in, const int* in_sizes, int n_in,
                              void* d_out, int out_size, void* d_ws, size_t ws_size,
                              hipStream_t stream) {
    const float* ctx   = (const float*)d_in[0];
    const int*   eos   = (const int*)d_in[1];
    const float* prior = (const float*)d_in[2];
    const float* Wq    = (const float*)d_in[3];
    const float* bq    = (const float*)d_in[4];
    const float* Wk    = (const float*)d_in[5];
    const float* bk    = (const float*)d_in[6];
    const float* gamma = (const float*)d_in[7];
    const float* beta  = (const float*)d_in[8];

    float* out_g  = (float*)d_out;
    float* out_na = out_g + (size_t)BB * SS * SS;

    char* ws = (char*)d_ws;
    __hip_bfloat16* x  = (__hip_bfloat16*)ws;                                // 16 MiB
    __hip_bfloat16* C  = (__hip_bfloat16*)(ws + (size_t)BS * DD * 2);        // 32 MiB
    __hip_bfloat16* WT = (__hip_bfloat16*)(ws + (size_t)BS * DD * 2
                                              + (size_t)BS * NN * 2);        // 4 MiB
    char* p2 = ws + (size_t)BS * DD * 2 + (size_t)BS * NN * 2 + (size_t)NN * DD * 2;
    float* biasc = (float*)p2;                 // 8 KiB
    float* vsub = biasc + NN;
    float* vsup = vsub + BS;
    float* wuni = vsup + BS;
    double* Lc = (double*)(wuni + BS);         // 64 KiB (8-byte aligned)

    ln_kernel<<<BS, 256, 0, stream>>>(ctx, gamma, beta, x);

    dim3 gp(DD / 32, NN / 32);
    prep_kernel<<<gp, 256, 0, stream>>>(Wq, Wk, WT);
    bias_kernel<<<NN / 256, 256, 0, stream>>>(bq, bk, biasc);

    dim3 gg(BS / TM, NN / TN);
    gemm_mfma<<<gg, 256, 0, stream>>>(x, WT, biasc, C);

    band_kernel<<<BS / 4, 256, 0, stream>>>(C, eos, vsub, vsup, wuni);

    scan_kernel<<<BB, 256, 0, stream>>>(prior, vsub, vsup, Lc);

    size_t total = (size_t)BB * SS * SS / 4;
    out_kernel<<<(int)(total / 256), 256, 0, stream>>>(prior, vsub, vsup, wuni, Lc,
                                                       out_g, out_na);
}